// Round 13
// baseline (145.250 us; speedup 1.0000x reference)
//
#include <hip/hip_runtime.h>
#include <math.h>

#define V 8
#define B 128
#define P 512
#define PPAD 528   // P + 16: prefetch overread pad
#define NE 75
#define REPS 8     // R13 diagnostic: replicate hot kernel to force profiler visibility

static constexpr float NU = 0.1f;
static constexpr float EPS = 1e-5f;
static constexpr float INV_SQRT2 = 0.70710678118654752440f;
static constexpr float L2E = 1.4426950408889634f;  // log2(e)

typedef float v4f __attribute__((ext_vector_type(4)));

__device__ __forceinline__ float fast_exp2(float x) {
#if __has_builtin(__builtin_amdgcn_exp2f)
  return __builtin_amdgcn_exp2f(x);
#else
  return exp2f(x);
#endif
}

__device__ __forceinline__ v4f v4fma(v4f a, v4f b, v4f c) {
#if __has_builtin(__builtin_elementwise_fma)
  return __builtin_elementwise_fma(a, b, c);
#else
  v4f r;
  r.x = fmaf(a.x, b.x, c.x); r.y = fmaf(a.y, b.y, c.y);
  r.z = fmaf(a.z, b.z, c.z); r.w = fmaf(a.w, b.w, c.w);
  return r;
#endif
}

// ---------------------------------------------------------------------------
// KA (hot): identical compute to R12 (best: 42.87us), but the grid is
// replicated REPS x (blockIdx = rep*1024 + tile); each rep writes its own
// A1t copy (no races; rep 0 feeds the tails). Purpose: aggregate dispatch
// ~8x20us >> 39us harness fills -> k_structure finally shows up in the
// rocprof top-5 WITH counters (VALUBusy / Occupancy / LDS conflicts decide
// the R14 branch; see theory).
// ---------------------------------------------------------------------------
__global__ __launch_bounds__(256, 4) void k_structure(
    const float2* __restrict__ pts2,      // [V,B,P] (birth,death)
    const int* __restrict__ lengths,      // [V,B]
    const float* __restrict__ centers,    // [V,NE,2] (transformed)
    const float* __restrict__ sharp,      // [V,NE,2]
    const float* __restrict__ c1w,        // [V,16,3]
    const float* __restrict__ c2w,        // [V,4,16]
    const float* __restrict__ l1w,        // [V,25,NE]
    const float* __restrict__ l1b,        // [V,25]
    float* __restrict__ A1t) {            // [REPS][V*25][B]
  int tile = blockIdx.x & 1023;
  int rep  = blockIdx.x >> 10;
  int i = tile >> 7;
  int b = tile & 127;
  int t = threadIdx.x;

  __shared__ float sS[3][PPAD], sY[3][PPAD];   // 12.7 KB
  __shared__ float slb[3][NE];
  __shared__ float hn[NE];

  int d0 = (i + V - 1) & (V - 1), d1 = i, d2 = (i + 1) & (V - 1);
  int len0 = lengths[d0 * B + b];
  int len1 = lengths[d1 * B + b];
  int len2 = lengths[d2 * B + b];

  for (int u = t; u < 3 * P; u += 256) {
    int jj = u >> 9;
    int pp = u & (P - 1);
    int d   = (jj == 0) ? d0 : (jj == 1) ? d1 : d2;
    int len = (jj == 0) ? len0 : (jj == 1) ? len1 : len2;
    float2 q = pts2[((size_t)d * B + b) * P + pp];
    float s = (q.x + q.y) * INV_SQRT2;
    float y = (q.y - q.x) * INV_SQRT2;
    if (y <= NU) y = __logf(fmaxf(y, 1e-12f) * 10.0f) + NU;
    if (pp >= len) { s = 1e9f; y = 1e9f; }  // exp2 -> 0 exactly
    sS[jj][pp] = s;
    sY[jj][pp] = y;
  }

  // wave-uniform (j,n) mapping
  int w = t >> 6, l = t & 63;
  int j, n;
  bool active;
  if (w < 3) {
    j = w;
    n = l;
    active = true;
  } else {
    active = (l < 33);
    int jl = l / 11;
    if (!active) jl = 2;
    j = jl;
    n = active ? (64 + (l - jl * 11)) : 74;
  }

  int ci = (i * NE + n) * 2;
  float a  = sharp[ci],   c  = sharp[ci + 1];
  float cs = centers[ci], cy = centers[ci + 1];
  float nA = -a * L2E;
  float nC = -c * L2E;
  float Bsc = 2.0f * a * cs * L2E;
  float Byc = 2.0f * c * cy * L2E;
  float nD = -(a * cs * cs + c * cy * cy) * L2E;
  v4f nA4 = {nA, nA, nA, nA}, nC4 = {nC, nC, nC, nC};
  v4f Bs4 = {Bsc, Bsc, Bsc, Bsc}, By4 = {Byc, Byc, Byc, Byc};
  v4f nD4 = {nD, nD, nD, nD};

  int mx = (w == 0) ? len0
         : (w == 1) ? len1
         : (w == 2) ? len2 : max(len0, max(len1, len2));
  int trip = (mx + 15) & ~15;

  __syncthreads();

  const float* Sj = sS[j];
  const float* Yj = sY[j];

  v4f cs0 = *(const v4f*)&Sj[0],  cs1 = *(const v4f*)&Sj[4];
  v4f cs2 = *(const v4f*)&Sj[8],  cs3 = *(const v4f*)&Sj[12];
  v4f cy0 = *(const v4f*)&Yj[0],  cy1 = *(const v4f*)&Yj[4];
  v4f cy2 = *(const v4f*)&Yj[8],  cy3 = *(const v4f*)&Yj[12];

  float ac0 = 0.f, ac1 = 0.f, ac2 = 0.f, ac3 = 0.f;
  float ac4 = 0.f, ac5 = 0.f, ac6 = 0.f, ac7 = 0.f;
  for (int p = 0; p < trip; p += 16) {
    v4f ns0 = *(const v4f*)&Sj[p + 16], ns1 = *(const v4f*)&Sj[p + 20];
    v4f ns2 = *(const v4f*)&Sj[p + 24], ns3 = *(const v4f*)&Sj[p + 28];
    v4f ny0 = *(const v4f*)&Yj[p + 16], ny1 = *(const v4f*)&Yj[p + 20];
    v4f ny2 = *(const v4f*)&Yj[p + 24], ny3 = *(const v4f*)&Yj[p + 28];

    v4f u0 = v4fma(nA4, cs0, Bs4), u1 = v4fma(nA4, cs1, Bs4);
    v4f u2 = v4fma(nA4, cs2, Bs4), u3 = v4fma(nA4, cs3, Bs4);
    v4f v0 = v4fma(nC4, cy0, By4), v1 = v4fma(nC4, cy1, By4);
    v4f v2 = v4fma(nC4, cy2, By4), v3 = v4fma(nC4, cy3, By4);
    v4f t0 = v4fma(cs0, u0, nD4),  t1 = v4fma(cs1, u1, nD4);
    v4f t2 = v4fma(cs2, u2, nD4),  t3 = v4fma(cs3, u3, nD4);
    v4f a0 = v4fma(cy0, v0, t0),   a1 = v4fma(cy1, v1, t1);
    v4f a2 = v4fma(cy2, v2, t2),   a3 = v4fma(cy3, v3, t3);
    ac0 += fast_exp2(a0.x); ac1 += fast_exp2(a0.y);
    ac2 += fast_exp2(a0.z); ac3 += fast_exp2(a0.w);
    ac4 += fast_exp2(a1.x); ac5 += fast_exp2(a1.y);
    ac6 += fast_exp2(a1.z); ac7 += fast_exp2(a1.w);
    ac0 += fast_exp2(a2.x); ac1 += fast_exp2(a2.y);
    ac2 += fast_exp2(a2.z); ac3 += fast_exp2(a2.w);
    ac4 += fast_exp2(a3.x); ac5 += fast_exp2(a3.y);
    ac6 += fast_exp2(a3.z); ac7 += fast_exp2(a3.w);

    cs0 = ns0; cs1 = ns1; cs2 = ns2; cs3 = ns3;
    cy0 = ny0; cy1 = ny1; cy2 = ny2; cy3 = ny3;
  }
  float accv = ((ac0 + ac1) + (ac2 + ac3)) + ((ac4 + ac5) + (ac6 + ac7));

  if (active) slb[j][n] = accv;
  __syncthreads();

  if (t < NE) {
    float s0 = slb[0][t], s1 = slb[1][t], s2 = slb[2][t];
    float a0 = 0, a1 = 0, a2 = 0, a3 = 0;
#pragma unroll
    for (int f = 0; f < 16; ++f) {
      float w0 = c1w[(i * 16 + f) * 3 + 0];
      float w1 = c1w[(i * 16 + f) * 3 + 1];
      float w2 = c1w[(i * 16 + f) * 3 + 2];
      float h1 = fmaf(w0, s0, fmaf(w1, s1, w2 * s2));
      a0 = fmaf(c2w[(i * 4 + 0) * 16 + f], h1, a0);
      a1 = fmaf(c2w[(i * 4 + 1) * 16 + f], h1, a1);
      a2 = fmaf(c2w[(i * 4 + 2) * 16 + f], h1, a2);
      a3 = fmaf(c2w[(i * 4 + 3) * 16 + f], h1, a3);
    }
    hn[t] = fmaxf(fmaxf(a0, a1), fmaxf(a2, a3));
  }
  __syncthreads();

  if (t < 25) {
    float acc = l1b[i * 25 + t];
    const float* wgt = l1w + ((size_t)i * 25 + t) * NE;
#pragma unroll 5
    for (int m = 0; m < NE; ++m) acc = fmaf(wgt[m], hn[m], acc);
    A1t[(size_t)rep * 200 * B + ((size_t)(i * 25 + t)) * B + b] = acc;
  }
}

// ---------------------------------------------------------------------------
// KB: bn1 + l2 + relu + fc1 (reads rep-0 A1t). Unchanged.
// ---------------------------------------------------------------------------
__global__ __launch_bounds__(256) void k_tail1(
    const float* __restrict__ A1t, const float* __restrict__ g1,
    const float* __restrict__ b1, const float* __restrict__ l2w,
    const float* __restrict__ l2b, const float* __restrict__ fc1w,
    const float* __restrict__ fc1b, float* __restrict__ Yt) {
  int b = blockIdx.x;
  int t = threadIdx.x;
  __shared__ float xin[200];
  __shared__ float Xl[200];

  if (t < 200) {
    const float4* col = (const float4*)(A1t + (size_t)t * B);
    float4 s4 = {0, 0, 0, 0}, q4 = {0, 0, 0, 0};
#pragma unroll
    for (int u = 0; u < B / 4; ++u) {
      float4 v = col[u];
      s4.x += v.x; s4.y += v.y; s4.z += v.z; s4.w += v.w;
      q4.x = fmaf(v.x, v.x, q4.x); q4.y = fmaf(v.y, v.y, q4.y);
      q4.z = fmaf(v.z, v.z, q4.z); q4.w = fmaf(v.w, v.w, q4.w);
    }
    float s = (s4.x + s4.y) + (s4.z + s4.w);
    float q = (q4.x + q4.y) + (q4.z + q4.w);
    float m = s * (1.0f / B);
    float var = q * (1.0f / B) - m * m;
    float r = rsqrtf(var + EPS);
    float v = A1t[(size_t)t * B + b];
    xin[t] = (v - m) * r * g1[t] + b1[t];
  }
  __syncthreads();
  if (t < 200) {
    int i = t / 25;
    float acc = l2b[t];
    const float* w = l2w + (size_t)t * 25;
    const float* x = xin + i * 25;
#pragma unroll
    for (int jj = 0; jj < 25; ++jj) acc = fmaf(w[jj], x[jj], acc);
    Xl[t] = fmaxf(acc, 0.0f);
  }
  __syncthreads();
  if (t < 100) {
    float acc = fc1b[t];
    const float* w = fc1w + (size_t)t * 200;
#pragma unroll 8
    for (int q = 0; q < 200; ++q) acc = fmaf(w[q], Xl[q], acc);
    Yt[(size_t)t * B + b] = acc;
  }
}

// ---------------------------------------------------------------------------
// KC: bn2 + fc2 -> out[B,70]. Unchanged.
// ---------------------------------------------------------------------------
__global__ __launch_bounds__(128) void k_tail2(
    const float* __restrict__ Yt, const float* __restrict__ g2,
    const float* __restrict__ b2, const float* __restrict__ fc2w,
    const float* __restrict__ fc2b, float* __restrict__ out) {
  int b = blockIdx.x;
  int t = threadIdx.x;
  __shared__ float yin[100];
  if (t < 100) {
    const float4* col = (const float4*)(Yt + (size_t)t * B);
    float4 s4 = {0, 0, 0, 0}, q4 = {0, 0, 0, 0};
#pragma unroll
    for (int u = 0; u < B / 4; ++u) {
      float4 v = col[u];
      s4.x += v.x; s4.y += v.y; s4.z += v.z; s4.w += v.w;
      q4.x = fmaf(v.x, v.x, q4.x); q4.y = fmaf(v.y, v.y, q4.y);
      q4.z = fmaf(v.z, v.z, q4.z); q4.w = fmaf(v.w, v.w, q4.w);
    }
    float s = (s4.x + s4.y) + (s4.z + s4.w);
    float q = (q4.x + q4.y) + (q4.z + q4.w);
    float m = s * (1.0f / B);
    float var = q * (1.0f / B) - m * m;
    float r = rsqrtf(var + EPS);
    float v = Yt[(size_t)t * B + b];
    yin[t] = (v - m) * r * g2[t] + b2[t];
  }
  __syncthreads();
  if (t < 70) {
    float acc = fc2b[t];
    const float* w = fc2w + (size_t)t * 100;
#pragma unroll 4
    for (int m = 0; m < 100; ++m) acc = fmaf(w[m], yin[m], acc);
    out[(size_t)b * 70 + t] = acc;
  }
}

// ---------------------------------------------------------------------------
extern "C" void kernel_launch(void* const* d_in, const int* in_sizes, int n_in,
                              void* d_out, int out_size, void* d_ws, size_t ws_size,
                              hipStream_t stream) {
  const float2* pts2   = (const float2*)d_in[0];
  const int*   lengths = (const int*)d_in[1];
  const float* centers = (const float*)d_in[2];
  const float* sharp   = (const float*)d_in[3];
  const float* c1w     = (const float*)d_in[4];
  const float* c2w     = (const float*)d_in[5];
  const float* l1w     = (const float*)d_in[6];
  const float* l1b     = (const float*)d_in[7];
  const float* bn1g    = (const float*)d_in[8];
  const float* bn1b    = (const float*)d_in[9];
  const float* l2w     = (const float*)d_in[10];
  const float* l2b     = (const float*)d_in[11];
  const float* fc1w    = (const float*)d_in[12];
  const float* fc1b    = (const float*)d_in[13];
  const float* fbn_g   = (const float*)d_in[14];
  const float* fbn_b   = (const float*)d_in[15];
  const float* fc2w    = (const float*)d_in[16];
  const float* fc2b    = (const float*)d_in[17];
  float* out = (float*)d_out;

  float* A1t = (float*)d_ws;                  // [REPS][200][128]; rep 0 is live
  float* Yt  = A1t + (size_t)REPS * 200 * B;  // [100][128]

  // DIAGNOSTIC: 8x replicated grid so k_structure's aggregate duration
  // (~160us) exceeds the ~39us harness fills -> top-1 in rocprof with
  // counters. Output correctness unchanged (rep 0 feeds tails).
  k_structure<<<dim3(REPS * V * B), dim3(256), 0, stream>>>(
      pts2, lengths, centers, sharp, c1w, c2w, l1w, l1b, A1t);
  k_tail1<<<dim3(B), dim3(256), 0, stream>>>(
      A1t, bn1g, bn1b, l2w, l2b, fc1w, fc1b, Yt);
  k_tail2<<<dim3(B), dim3(128), 0, stream>>>(
      Yt, fbn_g, fbn_b, fc2w, fc2b, out);
}

// Round 14
// 42.839 us; speedup vs baseline: 3.3906x; 3.3906x over previous
//
#include <hip/hip_runtime.h>
#include <math.h>

#define V 8
#define B 128
#define P 512
#define PPAD 528   // P + 16: prefetch overread pad
#define NE 75

static constexpr float NU = 0.1f;
static constexpr float EPS = 1e-5f;
static constexpr float INV_SQRT2 = 0.70710678118654752440f;
static constexpr float L2E = 1.4426950408889634f;  // log2(e)

typedef float v2f __attribute__((ext_vector_type(2)));
typedef float v4f __attribute__((ext_vector_type(4)));

__device__ __forceinline__ float fast_exp2(float x) {
#if __has_builtin(__builtin_amdgcn_exp2f)
  return __builtin_amdgcn_exp2f(x);
#else
  return exp2f(x);
#endif
}

// R14: packed f32 FMA (VOP3P). R13 counters showed the v4f elementwise fma
// was scalarized (420 cyc/iter fits 64 scalar v_fma, and VGPR=36); packing
// halves the FMA issue share (31% of VALU time).
__device__ __forceinline__ v2f pk_fma(v2f a, v2f b, v2f c) {
  v2f d;
  asm("v_pk_fma_f32 %0, %1, %2, %3" : "=v"(d) : "v"(a), "v"(b), "v"(c));
  return d;
}

__device__ __forceinline__ v2f lo2(v4f q) { return __builtin_shufflevector(q, q, 0, 1); }
__device__ __forceinline__ v2f hi2(v4f q) { return __builtin_shufflevector(q, q, 2, 3); }

// ---------------------------------------------------------------------------
// KA (hot): transform + masked Gaussian sums + conv1->conv2->max -> l1.
// Identical structure to R12 (best: 42.87us) except the quadratic-form chain
// runs on v_pk_fma_f32: per 2 points
//   u = pk_fma(nA,s,Bs); t = pk_fma(s,u,nD); v = pk_fma(nC,y,By);
//   arg = pk_fma(y,v,t)
// LDS reads stay ds_read_b128 (v4f), halves extracted as aligned v2f pairs.
// ---------------------------------------------------------------------------
__global__ __launch_bounds__(256, 4) void k_structure(
    const float2* __restrict__ pts2,      // [V,B,P] (birth,death)
    const int* __restrict__ lengths,      // [V,B]
    const float* __restrict__ centers,    // [V,NE,2] (transformed)
    const float* __restrict__ sharp,      // [V,NE,2]
    const float* __restrict__ c1w,        // [V,16,3]
    const float* __restrict__ c2w,        // [V,4,16]
    const float* __restrict__ l1w,        // [V,25,NE]
    const float* __restrict__ l1b,        // [V,25]
    float* __restrict__ A1t) {            // [V*25][B]
  int i = blockIdx.x >> 7;
  int b = blockIdx.x & 127;
  int t = threadIdx.x;

  __shared__ float sS[3][PPAD], sY[3][PPAD];   // 12.7 KB
  __shared__ float slb[3][NE];
  __shared__ float hn[NE];

  int d0 = (i + V - 1) & (V - 1), d1 = i, d2 = (i + 1) & (V - 1);
  int len0 = lengths[d0 * B + b];
  int len1 = lengths[d1 * B + b];
  int len2 = lengths[d2 * B + b];

  // ---- staging: load+transform 3 directions x 512 points ----
  for (int u = t; u < 3 * P; u += 256) {
    int jj = u >> 9;
    int pp = u & (P - 1);
    int d   = (jj == 0) ? d0 : (jj == 1) ? d1 : d2;
    int len = (jj == 0) ? len0 : (jj == 1) ? len1 : len2;
    float2 q = pts2[((size_t)d * B + b) * P + pp];
    float s = (q.x + q.y) * INV_SQRT2;
    float y = (q.y - q.x) * INV_SQRT2;
    if (y <= NU) y = __logf(fmaxf(y, 1e-12f) * 10.0f) + NU;
    if (pp >= len) { s = 1e9f; y = 1e9f; }  // exp2 -> 0 exactly
    sS[jj][pp] = s;
    sY[jj][pp] = y;
  }

  // wave-uniform (j,n) mapping (R7): one j per full wave -> broadcast reads
  int w = t >> 6, l = t & 63;
  int j, n;
  bool active;
  if (w < 3) {
    j = w;
    n = l;
    active = true;
  } else {
    active = (l < 33);
    int jl = l / 11;
    if (!active) jl = 2;
    j = jl;
    n = active ? (64 + (l - jl * 11)) : 74;
  }

  int ci = (i * NE + n) * 2;
  float a  = sharp[ci],   c  = sharp[ci + 1];
  float cs = centers[ci], cy = centers[ci + 1];
  float nA = -a * L2E;
  float nC = -c * L2E;
  float Bsc = 2.0f * a * cs * L2E;
  float Byc = 2.0f * c * cy * L2E;
  float nD = -(a * cs * cs + c * cy * cy) * L2E;
  v2f nA2 = {nA, nA}, nC2 = {nC, nC};
  v2f Bs2 = {Bsc, Bsc}, By2 = {Byc, Byc}, nD2 = {nD, nD};

  int mx = (w == 0) ? len0
         : (w == 1) ? len1
         : (w == 2) ? len2 : max(len0, max(len1, len2));
  int trip = (mx + 15) & ~15;   // 16 points per iteration

  __syncthreads();

  const float* Sj = sS[j];
  const float* Yj = sY[j];

  float ac0 = 0.f, ac1 = 0.f, ac2 = 0.f, ac3 = 0.f;
  float ac4 = 0.f, ac5 = 0.f, ac6 = 0.f, ac7 = 0.f;
  for (int p = 0; p < trip; p += 16) {
    v4f Sq0 = *(const v4f*)&Sj[p],     Sq1 = *(const v4f*)&Sj[p + 4];
    v4f Sq2 = *(const v4f*)&Sj[p + 8], Sq3 = *(const v4f*)&Sj[p + 12];
    v4f Yq0 = *(const v4f*)&Yj[p],     Yq1 = *(const v4f*)&Yj[p + 4];
    v4f Yq2 = *(const v4f*)&Yj[p + 8], Yq3 = *(const v4f*)&Yj[p + 12];

    v2f s0 = lo2(Sq0), s1 = hi2(Sq0), s2 = lo2(Sq1), s3 = hi2(Sq1);
    v2f s4 = lo2(Sq2), s5 = hi2(Sq2), s6 = lo2(Sq3), s7 = hi2(Sq3);
    v2f y0 = lo2(Yq0), y1 = hi2(Yq0), y2 = lo2(Yq1), y3 = hi2(Yq1);
    v2f y4 = lo2(Yq2), y5 = hi2(Yq2), y6 = lo2(Yq3), y7 = hi2(Yq3);

    // arg = y*(nC*y+By) + (s*(nA*s+Bs) + nD), all packed 2-wide
    v2f u0 = pk_fma(nA2, s0, Bs2), u1 = pk_fma(nA2, s1, Bs2);
    v2f u2 = pk_fma(nA2, s2, Bs2), u3 = pk_fma(nA2, s3, Bs2);
    v2f u4 = pk_fma(nA2, s4, Bs2), u5 = pk_fma(nA2, s5, Bs2);
    v2f u6 = pk_fma(nA2, s6, Bs2), u7 = pk_fma(nA2, s7, Bs2);
    v2f v0 = pk_fma(nC2, y0, By2), v1 = pk_fma(nC2, y1, By2);
    v2f v2 = pk_fma(nC2, y2, By2), v3 = pk_fma(nC2, y3, By2);
    v2f v4 = pk_fma(nC2, y4, By2), v5 = pk_fma(nC2, y5, By2);
    v2f v6 = pk_fma(nC2, y6, By2), v7 = pk_fma(nC2, y7, By2);
    v2f t0 = pk_fma(s0, u0, nD2),  t1 = pk_fma(s1, u1, nD2);
    v2f t2 = pk_fma(s2, u2, nD2),  t3 = pk_fma(s3, u3, nD2);
    v2f t4 = pk_fma(s4, u4, nD2),  t5 = pk_fma(s5, u5, nD2);
    v2f t6 = pk_fma(s6, u6, nD2),  t7 = pk_fma(s7, u7, nD2);
    v2f a0 = pk_fma(y0, v0, t0),   a1 = pk_fma(y1, v1, t1);
    v2f a2 = pk_fma(y2, v2, t2),   a3 = pk_fma(y3, v3, t3);
    v2f a4 = pk_fma(y4, v4, t4),   a5 = pk_fma(y5, v5, t5);
    v2f a6 = pk_fma(y6, v6, t6),   a7 = pk_fma(y7, v7, t7);

    ac0 += fast_exp2(a0.x); ac1 += fast_exp2(a0.y);
    ac2 += fast_exp2(a1.x); ac3 += fast_exp2(a1.y);
    ac4 += fast_exp2(a2.x); ac5 += fast_exp2(a2.y);
    ac6 += fast_exp2(a3.x); ac7 += fast_exp2(a3.y);
    ac0 += fast_exp2(a4.x); ac1 += fast_exp2(a4.y);
    ac2 += fast_exp2(a5.x); ac3 += fast_exp2(a5.y);
    ac4 += fast_exp2(a6.x); ac5 += fast_exp2(a6.y);
    ac6 += fast_exp2(a7.x); ac7 += fast_exp2(a7.y);
  }
  float accv = ((ac0 + ac1) + (ac2 + ac3)) + ((ac4 + ac5) + (ac6 + ac7));

  if (active) slb[j][n] = accv;
  __syncthreads();

  // ---- head: conv1(3->16) -> conv2(16->4) -> channel-max ----
  if (t < NE) {
    float s0 = slb[0][t], s1 = slb[1][t], s2 = slb[2][t];
    float a0 = 0, a1 = 0, a2 = 0, a3 = 0;
#pragma unroll
    for (int f = 0; f < 16; ++f) {
      float w0 = c1w[(i * 16 + f) * 3 + 0];
      float w1 = c1w[(i * 16 + f) * 3 + 1];
      float w2 = c1w[(i * 16 + f) * 3 + 2];
      float h1 = fmaf(w0, s0, fmaf(w1, s1, w2 * s2));
      a0 = fmaf(c2w[(i * 4 + 0) * 16 + f], h1, a0);
      a1 = fmaf(c2w[(i * 4 + 1) * 16 + f], h1, a1);
      a2 = fmaf(c2w[(i * 4 + 2) * 16 + f], h1, a2);
      a3 = fmaf(c2w[(i * 4 + 3) * 16 + f], h1, a3);
    }
    hn[t] = fmaxf(fmaxf(a0, a1), fmaxf(a2, a3));
  }
  __syncthreads();

  if (t < 25) {
    float acc = l1b[i * 25 + t];
    const float* wgt = l1w + ((size_t)i * 25 + t) * NE;
#pragma unroll 5
    for (int m = 0; m < NE; ++m) acc = fmaf(wgt[m], hn[m], acc);
    A1t[((size_t)(i * 25 + t)) * B + b] = acc;
  }
}

// ---------------------------------------------------------------------------
// KB: bn1 (redundant per-block batch stats from L2) + l2(25x25)+relu + fc1.
// ---------------------------------------------------------------------------
__global__ __launch_bounds__(256) void k_tail1(
    const float* __restrict__ A1t, const float* __restrict__ g1,
    const float* __restrict__ b1, const float* __restrict__ l2w,
    const float* __restrict__ l2b, const float* __restrict__ fc1w,
    const float* __restrict__ fc1b, float* __restrict__ Yt) {
  int b = blockIdx.x;
  int t = threadIdx.x;
  __shared__ float xin[200];
  __shared__ float Xl[200];

  if (t < 200) {
    const float4* col = (const float4*)(A1t + (size_t)t * B);
    float4 s4 = {0, 0, 0, 0}, q4 = {0, 0, 0, 0};
#pragma unroll
    for (int u = 0; u < B / 4; ++u) {
      float4 v = col[u];
      s4.x += v.x; s4.y += v.y; s4.z += v.z; s4.w += v.w;
      q4.x = fmaf(v.x, v.x, q4.x); q4.y = fmaf(v.y, v.y, q4.y);
      q4.z = fmaf(v.z, v.z, q4.z); q4.w = fmaf(v.w, v.w, q4.w);
    }
    float s = (s4.x + s4.y) + (s4.z + s4.w);
    float q = (q4.x + q4.y) + (q4.z + q4.w);
    float m = s * (1.0f / B);
    float var = q * (1.0f / B) - m * m;
    float r = rsqrtf(var + EPS);
    float v = A1t[(size_t)t * B + b];
    xin[t] = (v - m) * r * g1[t] + b1[t];
  }
  __syncthreads();
  if (t < 200) {
    int i = t / 25;
    float acc = l2b[t];
    const float* w = l2w + (size_t)t * 25;
    const float* x = xin + i * 25;
#pragma unroll
    for (int jj = 0; jj < 25; ++jj) acc = fmaf(w[jj], x[jj], acc);
    Xl[t] = fmaxf(acc, 0.0f);
  }
  __syncthreads();
  if (t < 100) {
    float acc = fc1b[t];
    const float* w = fc1w + (size_t)t * 200;
#pragma unroll 8
    for (int q = 0; q < 200; ++q) acc = fmaf(w[q], Xl[q], acc);
    Yt[(size_t)t * B + b] = acc;
  }
}

// ---------------------------------------------------------------------------
// KC: bn2 (redundant per-block stats) + fc2 -> out[B,70]
// ---------------------------------------------------------------------------
__global__ __launch_bounds__(128) void k_tail2(
    const float* __restrict__ Yt, const float* __restrict__ g2,
    const float* __restrict__ b2, const float* __restrict__ fc2w,
    const float* __restrict__ fc2b, float* __restrict__ out) {
  int b = blockIdx.x;
  int t = threadIdx.x;
  __shared__ float yin[100];
  if (t < 100) {
    const float4* col = (const float4*)(Yt + (size_t)t * B);
    float4 s4 = {0, 0, 0, 0}, q4 = {0, 0, 0, 0};
#pragma unroll
    for (int u = 0; u < B / 4; ++u) {
      float4 v = col[u];
      s4.x += v.x; s4.y += v.y; s4.z += v.z; s4.w += v.w;
      q4.x = fmaf(v.x, v.x, q4.x); q4.y = fmaf(v.y, v.y, q4.y);
      q4.z = fmaf(v.z, v.z, q4.z); q4.w = fmaf(v.w, v.w, q4.w);
    }
    float s = (s4.x + s4.y) + (s4.z + s4.w);
    float q = (q4.x + q4.y) + (q4.z + q4.w);
    float m = s * (1.0f / B);
    float var = q * (1.0f / B) - m * m;
    float r = rsqrtf(var + EPS);
    float v = Yt[(size_t)t * B + b];
    yin[t] = (v - m) * r * g2[t] + b2[t];
  }
  __syncthreads();
  if (t < 70) {
    float acc = fc2b[t];
    const float* w = fc2w + (size_t)t * 100;
#pragma unroll 4
    for (int m = 0; m < 100; ++m) acc = fmaf(w[m], yin[m], acc);
    out[(size_t)b * 70 + t] = acc;
  }
}

// ---------------------------------------------------------------------------
extern "C" void kernel_launch(void* const* d_in, const int* in_sizes, int n_in,
                              void* d_out, int out_size, void* d_ws, size_t ws_size,
                              hipStream_t stream) {
  const float2* pts2   = (const float2*)d_in[0];
  const int*   lengths = (const int*)d_in[1];
  const float* centers = (const float*)d_in[2];
  const float* sharp   = (const float*)d_in[3];
  const float* c1w     = (const float*)d_in[4];
  const float* c2w     = (const float*)d_in[5];
  const float* l1w     = (const float*)d_in[6];
  const float* l1b     = (const float*)d_in[7];
  const float* bn1g    = (const float*)d_in[8];
  const float* bn1b    = (const float*)d_in[9];
  const float* l2w     = (const float*)d_in[10];
  const float* l2b     = (const float*)d_in[11];
  const float* fc1w    = (const float*)d_in[12];
  const float* fc1b    = (const float*)d_in[13];
  const float* fbn_g   = (const float*)d_in[14];
  const float* fbn_b   = (const float*)d_in[15];
  const float* fc2w    = (const float*)d_in[16];
  const float* fc2b    = (const float*)d_in[17];
  float* out = (float*)d_out;

  float* A1t = (float*)d_ws;          // [200][128]
  float* Yt  = A1t + 200 * B;         // [100][128]

  k_structure<<<dim3(V * B), dim3(256), 0, stream>>>(
      pts2, lengths, centers, sharp, c1w, c2w, l1w, l1b, A1t);
  k_tail1<<<dim3(B), dim3(256), 0, stream>>>(
      A1t, bn1g, bn1b, l2w, l2b, fc1w, fc1b, Yt);
  k_tail2<<<dim3(B), dim3(128), 0, stream>>>(
      Yt, fbn_g, fbn_b, fc2w, fc2b, out);
}